// Round 1
// baseline (644.833 us; speedup 1.0000x reference)
//
#include <hip/hip_runtime.h>
#include <math.h>

#define N_  4
#define P_  20000
#define DIN 1024
#define K_  8
#define DH  64
#define BP  64      // patches per block
#define BD  64      // d-chunk
#define XS  68      // padded LDS stride for x tile (68 % 32 == 4 -> conflict-free 16-row reads)

// ws layout (floats):
//   [0, 2048)      gsum  : per-(n,k,j) unnormalized cluster sums (N*K*DH)
//   [2048, 2080)   gcnt  : per-(n,k) patch counts (as int)
//   [2080, 2088)   c2    : ||centroid_k||^2

__global__ __launch_bounds__(512) void k_init(const float* __restrict__ centroids,
                                              float* __restrict__ ws) {
  const int t = threadIdx.x;
  float* gsum = ws;
  int*   gcnt = (int*)(ws + 2048);
  float* c2   = ws + 2080;
  for (int i = t; i < N_ * K_ * DH; i += 512) gsum[i] = 0.f;
  if (t < N_ * K_) gcnt[t] = 0;
  // 8 waves, one per centroid: reduce sum of squares over 1024 dims
  const int w = t >> 6, lane = t & 63;
  float s = 0.f;
  for (int d = lane; d < DIN; d += 64) {
    float v = centroids[w * DIN + d];
    s += v * v;
  }
  for (int off = 32; off > 0; off >>= 1) s += __shfl_down(s, off, 64);
  if (lane == 0) c2[w] = s;
}

__global__ __launch_bounds__(256) void k_main(
    const float* __restrict__ x, const float* __restrict__ centroids,
    const float* __restrict__ W_pre, const float* __restrict__ b_pre,
    float* __restrict__ out1, float* __restrict__ out2, float* __restrict__ ws) {
  __shared__ float xt[BP * XS];      // x tile / later xp tile
  __shared__ float wt[BD * DH];      // W_pre chunk, [d][j] layout
  __shared__ float ct[K_ * XS];      // centroid chunk
  __shared__ float sdist[BP * 9];    // per-patch dot(x,c_k) k<8; k==8 -> dot(x,x)
  __shared__ int   assign_s[BP];
  __shared__ int   cnt8[K_];

  const int t  = threadIdx.x;
  const int n  = blockIdx.y;
  const int p0 = blockIdx.x * BP;
  const int tx = t & 15;             // patch sub-index (16 consecutive rows per wave)
  const int tz = (t >> 4) & 3;
  const int w  = t >> 6;
  const int jb = 16 * w + 4 * tz;    // 4 contiguous j's per thread

  float* gsum = ws;
  int*   gcnt = (int*)(ws + 2048);
  const float* c2 = ws + 2080;

  for (int i = t; i < BP * 9; i += 256) sdist[i] = 0.f;
  if (t < K_) cnt8[t] = 0;

  float acc[4][4];
#pragma unroll
  for (int i = 0; i < 4; ++i)
#pragma unroll
    for (int jj = 0; jj < 4; ++jj) acc[i][jj] = 0.f;

  const int r  = t >> 4;
  const int c4 = (t & 15) << 2;

  for (int d0 = 0; d0 < DIN; d0 += BD) {
    __syncthreads();   // previous-iteration readers done before restage
    // stage x tile: 64 rows x 64 cols, padded stride
#pragma unroll
    for (int rr = 0; rr < 4; ++rr) {
      const int p = r + 16 * rr;
      float4 v = make_float4(0.f, 0.f, 0.f, 0.f);
      if (p0 + p < P_)
        v = *(const float4*)&x[(size_t)(n * P_ + p0 + p) * DIN + d0 + c4];
      *(float4*)&xt[p * XS + c4] = v;
    }
    // stage W chunk [d][j] (no pad; reads use 4-row broadcast pattern -> conflict-free)
#pragma unroll
    for (int rr = 0; rr < 4; ++rr) {
      const int d = r + 16 * rr;
      *(float4*)&wt[d * DH + c4] = *(const float4*)&W_pre[(size_t)(d0 + d) * DH + c4];
    }
    // stage centroid chunk
    if (t < 128) {
      const int k = t >> 4;
      *(float4*)&ct[k * XS + c4] = *(const float4*)&centroids[(size_t)k * DIN + d0 + c4];
    }
    __syncthreads();

    // 4x4 micro-tile FMA over this d-chunk
    for (int dd = 0; dd < BD; dd += 4) {
      float xv[4][4], wv[4][4];
#pragma unroll
      for (int i = 0; i < 4; ++i)
        *(float4*)&xv[i][0] = *(const float4*)&xt[(tx + 16 * i) * XS + dd];
#pragma unroll
      for (int q = 0; q < 4; ++q)
        *(float4*)&wv[q][0] = *(const float4*)&wt[(dd + q) * DH + jb];
#pragma unroll
      for (int i = 0; i < 4; ++i)
#pragma unroll
        for (int jj = 0; jj < 4; ++jj)
#pragma unroll
          for (int q = 0; q < 4; ++q)
            acc[i][jj] += xv[i][q] * wv[q][jj];
    }

    // distance partial dots: 64 patches x (8 centroids + self)
    for (int task = t; task < BP * 9; task += 256) {
      const int p = task / 9;
      const int k = task - 9 * p;
      const float* a = &xt[p * XS];
      const float* b = (k < 8) ? &ct[k * XS] : a;
      float s = 0.f;
#pragma unroll
      for (int dd = 0; dd < BD; dd += 4) {
        float4 av = *(const float4*)&a[dd];
        float4 bv = *(const float4*)&b[dd];
        s += av.x * bv.x + av.y * bv.y + av.z * bv.z + av.w * bv.w;
      }
      sdist[task] += s;
    }
  }
  __syncthreads();

  // hard assignment = argmin d2 (softmax(1e7/dist)>0.5 is one-hot at nearest centroid)
  if (t < BP) {
    int a = -1;
    if (p0 + t < P_) {
      const float x2 = sdist[t * 9 + 8];
      float best = 3.4e38f;
      int bk = 0;
#pragma unroll
      for (int k = 0; k < K_; ++k) {
        const float d2 = x2 + c2[k] - 2.f * sdist[t * 9 + k];
        if (d2 < best) { best = d2; bk = k; }
      }
      a = bk;
      atomicAdd(&cnt8[bk], 1);
    }
    assign_s[t] = a;
  }

  // epilogue: bias + relu, write enc_seq (twice) and xp tile into LDS (reuse xt)
  const float4 bp4 = *(const float4*)&b_pre[jb];
  const float bpf[4] = {bp4.x, bp4.y, bp4.z, bp4.w};
#pragma unroll
  for (int i = 0; i < 4; ++i) {
    const int p = tx + 16 * i;
    float v[4];
#pragma unroll
    for (int jj = 0; jj < 4; ++jj) {
      const float u = acc[i][jj] + bpf[jj];
      v[jj] = u > 0.f ? u : 0.f;
    }
    *(float4*)&xt[p * XS + jb] = *(const float4*)v;
    if (p0 + p < P_) {
      const size_t o = (size_t)(n * P_ + p0 + p) * DH + jb;
      *(float4*)&out1[o] = *(const float4*)v;
      *(float4*)&out2[o] = *(const float4*)v;
    }
  }
  __syncthreads();

  // per-block cluster sums -> one atomic per (k,j)
  for (int task = t; task < K_ * DH; task += 256) {
    const int k = task >> 6;
    const int j = task & 63;
    float s = 0.f;
    for (int p = 0; p < BP; ++p)
      s += (assign_s[p] == k) ? xt[p * XS + j] : 0.f;
    if (s != 0.f) atomicAdd(&gsum[(n * K_ + k) * DH + j], s);
  }
  if (t < K_ && cnt8[t] > 0) atomicAdd(&gcnt[n * K_ + t], cnt8[t]);
}

__global__ __launch_bounds__(256) void k_final(
    const float* __restrict__ W_a1, const float* __restrict__ b_a1,
    const float* __restrict__ W_a2, const float* __restrict__ b_a2,
    const float* __restrict__ W_out, const float* __restrict__ b_out,
    const float* __restrict__ ws, float* __restrict__ enc_cls) {
  __shared__ float xc[N_ * K_ * DH];
  __shared__ float wa[N_ * K_];
  __shared__ float As[N_ * K_];
  __shared__ int   cnts[N_ * K_];
  __shared__ float pooled[N_ * DH];
  const int t = threadIdx.x;
  const float* gsum = ws;
  const int* gcnt = (const int*)(ws + 2048);

  if (t < N_ * K_) cnts[t] = gcnt[t];
  __syncthreads();
  for (int i = t; i < N_ * K_ * DH; i += 256) {
    const int nk = i >> 6;
    const int c = cnts[nk];
    xc[i] = (c > 0) ? gsum[i] / (float)c : 0.f;
  }
  __syncthreads();
  // attention logits: A[n,k] = tanh(x_cls @ W_a1 + b_a1) @ W_a2 + b_a2
  if (t < N_ * K_) {
    float a = b_a2[0];
    for (int h = 0; h < 32; ++h) {
      float z = b_a1[h];
      for (int j = 0; j < DH; ++j) z += xc[t * DH + j] * W_a1[j * 32 + h];
      a += tanhf(z) * W_a2[h];
    }
    As[t] = (cnts[t] > 0) ? a : -100000.f;
  }
  __syncthreads();
  if (t < N_) {
    float m = -3.4e38f;
    for (int k = 0; k < K_; ++k) m = fmaxf(m, As[t * K_ + k]);
    float ssum = 0.f;
    float e[K_];
    for (int k = 0; k < K_; ++k) { e[k] = expf(As[t * K_ + k] - m); ssum += e[k]; }
    for (int k = 0; k < K_; ++k) wa[t * K_ + k] = e[k] / ssum;
  }
  __syncthreads();
  {
    const int n = t >> 6, j = t & 63;
    float s = 0.f;
    for (int k = 0; k < K_; ++k) s += xc[(n * K_ + k) * DH + j] * wa[n * K_ + k];
    pooled[t] = s;
  }
  __syncthreads();
  if (t < N_ * 32) {
    const int n = t >> 5, o = t & 31;
    float s = b_out[o];
    for (int j = 0; j < DH; ++j) s += pooled[n * DH + j] * W_out[j * 32 + o];
    enc_cls[n * 32 + o] = fmaxf(s, 0.f);
  }
}

extern "C" void kernel_launch(void* const* d_in, const int* in_sizes, int n_in,
                              void* d_out, int out_size, void* d_ws, size_t ws_size,
                              hipStream_t stream) {
  const float* x         = (const float*)d_in[0];
  const float* centroids = (const float*)d_in[1];
  const float* W_pre     = (const float*)d_in[2];
  const float* b_pre     = (const float*)d_in[3];
  const float* W_a1      = (const float*)d_in[4];
  const float* b_a1      = (const float*)d_in[5];
  const float* W_a2      = (const float*)d_in[6];
  const float* b_a2      = (const float*)d_in[7];
  const float* W_out     = (const float*)d_in[8];
  const float* b_out     = (const float*)d_in[9];

  float* out     = (float*)d_out;
  float* ws      = (float*)d_ws;
  float* enc_cls = out;                                   // [4,32]
  float* out1    = out + N_ * 32;                         // enc_seq copy 1
  float* out2    = out + N_ * 32 + (size_t)N_ * P_ * DH;  // enc_seq copy 2

  hipLaunchKernelGGL(k_init, dim3(1), dim3(512), 0, stream, centroids, ws);
  hipLaunchKernelGGL(k_main, dim3((P_ + BP - 1) / BP, N_), dim3(256), 0, stream,
                     x, centroids, W_pre, b_pre, out1, out2, ws);
  hipLaunchKernelGGL(k_final, dim3(1), dim3(256), 0, stream,
                     W_a1, b_a1, W_a2, b_a2, W_out, b_out, ws, enc_cls);
}

// Round 2
// 620.143 us; speedup vs baseline: 1.0398x; 1.0398x over previous
//
#include <hip/hip_runtime.h>
#include <math.h>

#define N_  4
#define P_  20000
#define DIN 1024
#define K_  8
#define DH  64
#define BP  128     // patches per block
#define NT  5       // 5 col-tiles of 16: cols 0-63 = W_pre, 64-71 = centroids, 72-79 pad

typedef float  f32x4 __attribute__((ext_vector_type(4)));
typedef short  s16x8 __attribute__((ext_vector_type(8)));
typedef unsigned int u32x4 __attribute__((ext_vector_type(4)));
typedef unsigned short ushort_t;

// ws layout (float offsets). NEEDS ws_size >= 344064 bytes.
//   [0,2048)      gsum   per-(n,k,j) cluster sums
//   [2048,2080)   gcnt   per-(n,k) counts (int)
//   [2080,2088)   c2     ||centroid_k||^2
//   [4096,45056)  Bth    bf16-hi plane of B^T  [80 cols][1024 k] (ushort)
//   [45056,86016) Btl    bf16-lo plane of B^T  (ushort)

union FragU { u32x4 u; s16x8 s; };

// Build B^T hi/lo bf16 planes: B[d][c] = W_pre[d][c] (c<64), centroids[c-64][d] (64<=c<72), else 0
__global__ __launch_bounds__(256) void k_prep(const float* __restrict__ W_pre,
                                              const float* __restrict__ centroids,
                                              float* __restrict__ ws) {
  const int c = blockIdx.x;          // 0..79
  const int t = threadIdx.x;
  ushort_t* Bth = (ushort_t*)(ws + 4096);
  ushort_t* Btl = (ushort_t*)(ws + 45056);
  for (int d = t; d < DIN; d += 256) {
    float v = 0.f;
    if (c < 64)      v = W_pre[(size_t)d * DH + c];
    else if (c < 72) v = centroids[(size_t)(c - 64) * DIN + d];
    unsigned u = __float_as_uint(v);
    unsigned r = u + 0x7FFFu + ((u >> 16) & 1u);     // RTN to bf16
    unsigned hb = r & 0xFFFF0000u;
    float lo = v - __uint_as_float(hb);
    unsigned ul = __float_as_uint(lo);
    unsigned rl = ul + 0x7FFFu + ((ul >> 16) & 1u);
    Bth[(size_t)c * DIN + d] = (ushort_t)(hb >> 16);
    Btl[(size_t)c * DIN + d] = (ushort_t)(rl >> 16);
  }
}

__global__ __launch_bounds__(512) void k_init2(const float* __restrict__ centroids,
                                               float* __restrict__ ws) {
  const int t = threadIdx.x;
  int* gcnt = (int*)(ws + 2048);
  for (int i = t; i < N_ * K_ * DH; i += 512) ws[i] = 0.f;
  if (t < N_ * K_) gcnt[t] = 0;
  const int w = t >> 6, lane = t & 63;
  float s = 0.f;
  for (int d = lane; d < DIN; d += 64) {
    float v = centroids[(size_t)w * DIN + d];
    s += v * v;
  }
  for (int off = 32; off > 0; off >>= 1) s += __shfl_down(s, off, 64);
  if (lane == 0) ws[2080 + w] = s;
}

__global__ __launch_bounds__(256) void k_main(
    const float* __restrict__ x, const float* __restrict__ b_pre,
    float* __restrict__ out1, float* __restrict__ out2, float* __restrict__ ws) {
  __shared__ float xt[BP * 68];     // x chunk fp32 (stride 68); reused as xp tile (stride 65)
  __shared__ float sc[BP * 9];      // per-patch scores c2-2dot
  __shared__ int   assign_s[BP];
  __shared__ int   cnt8[K_];
  __shared__ float c2s[K_];

  const int t = threadIdx.x;
  const int w = t >> 6, l = t & 63;
  const int n = blockIdx.y;
  const int p0 = blockIdx.x * BP;
  const int validP = (P_ - p0) < BP ? (P_ - p0) : BP;

  const ushort_t* Bth = (const ushort_t*)(ws + 4096);
  const ushort_t* Btl = (const ushort_t*)(ws + 45056);

  if (t < K_) { cnt8[t] = 0; c2s[t] = ws[2080 + t]; }

  f32x4 acc[2][NT];
#pragma unroll
  for (int rg = 0; rg < 2; ++rg)
#pragma unroll
    for (int tl = 0; tl < NT; ++tl) acc[rg][tl] = (f32x4){0.f, 0.f, 0.f, 0.f};

  const float* xbase = x + (size_t)n * P_ * DIN;
  const int quad8 = (l >> 4) << 3;   // k-offset of this lane's 8-element group

  for (int ch = 0; ch < 16; ++ch) {          // 16 chunks of 64 k
    const int d0 = ch * 64;
    __syncthreads();
    // stage: 128 rows x 64 k fp32, stride 68 (conflict-free, 2-way max)
#pragma unroll
    for (int i = 0; i < 8; ++i) {
      const int idx = t + 256 * i;
      const int row = idx >> 4, c4 = (idx & 15) << 2;
      int gp = p0 + row; gp = gp < P_ ? gp : P_ - 1;
      f32x4 v = *(const f32x4*)(xbase + (size_t)gp * DIN + d0 + c4);
      *(f32x4*)(xt + row * 68 + c4) = v;
    }
    __syncthreads();

#pragma unroll
    for (int kk = 0; kk < 2; ++kk) {         // 2 mfma K-steps of 32
      const int kb = d0 + kk * 32 + quad8;
      // B frags (global, L1/L2-resident; lanes l and l+16 share 64B lines)
      FragU bh[NT], bl[NT];
#pragma unroll
      for (int tl = 0; tl < NT; ++tl) {
        const size_t off = (size_t)(tl * 16 + (l & 15)) * DIN + kb;
        bh[tl].u = *(const u32x4*)(Bth + off);
        bl[tl].u = *(const u32x4*)(Btl + off);
      }
#pragma unroll
      for (int rg = 0; rg < 2; ++rg) {
        const int row = 32 * w + 16 * rg + (l & 15);
        const float* ap = xt + row * 68 + kk * 32 + quad8;
        f32x4 a0 = *(const f32x4*)ap;
        f32x4 a1 = *(const f32x4*)(ap + 4);
        float f[8];
#pragma unroll
        for (int e = 0; e < 4; ++e) { f[e] = a0[e]; f[4 + e] = a1[e]; }
        FragU ah, al;
#pragma unroll
        for (int q = 0; q < 4; ++q) {
          const unsigned u0 = __float_as_uint(f[2 * q]);
          const unsigned u1 = __float_as_uint(f[2 * q + 1]);
          ah.u[q] = (u0 >> 16) | (u1 & 0xFFFF0000u);           // hi = trunc-bf16
          const float l0 = f[2 * q]     - __uint_as_float(u0 & 0xFFFF0000u);
          const float l1 = f[2 * q + 1] - __uint_as_float(u1 & 0xFFFF0000u);
          al.u[q] = (__float_as_uint(l0) >> 16) | (__float_as_uint(l1) & 0xFFFF0000u);
        }
#pragma unroll
        for (int tl = 0; tl < NT; ++tl) {
          acc[rg][tl] = __builtin_amdgcn_mfma_f32_16x16x32_bf16(ah.s, bh[tl].s, acc[rg][tl], 0, 0, 0);
          acc[rg][tl] = __builtin_amdgcn_mfma_f32_16x16x32_bf16(ah.s, bl[tl].s, acc[rg][tl], 0, 0, 0);
          acc[rg][tl] = __builtin_amdgcn_mfma_f32_16x16x32_bf16(al.s, bh[tl].s, acc[rg][tl], 0, 0, 0);
        }
      }
    }
  }
  __syncthreads();   // all LDS x reads done; reuse xt as xp tile

  // epilogue: bias+relu, write enc_seq twice, xp->LDS (stride 65)
#pragma unroll
  for (int tl = 0; tl < 4; ++tl) {
    const int col = tl * 16 + (l & 15);
    const float bb = b_pre[col];
#pragma unroll
    for (int rg = 0; rg < 2; ++rg) {
#pragma unroll
      for (int r = 0; r < 4; ++r) {
        const int row = 32 * w + 16 * rg + ((l >> 4) << 2) + r;   // C layout: row=(lane>>4)*4+reg
        float v = acc[rg][tl][r] + bb;
        v = v > 0.f ? v : 0.f;
        xt[row * 65 + col] = v;
        if (row < validP) {
          const size_t o = (((size_t)(n * P_ + p0 + row)) << 6) + col;
          out1[o] = v;
          out2[o] = v;
        }
      }
    }
  }
  // scores from col-tile 4 (cols 64-71 = centroid dots)
  if ((l & 15) < K_) {
    const int k = l & 15;
#pragma unroll
    for (int rg = 0; rg < 2; ++rg)
#pragma unroll
      for (int r = 0; r < 4; ++r) {
        const int row = 32 * w + 16 * rg + ((l >> 4) << 2) + r;
        sc[row * 9 + k] = c2s[k] - 2.f * acc[rg][4][r];
      }
  }
  __syncthreads();

  if (t < BP) {
    int a = -1;
    if (t < validP) {
      float best = 3.4e38f; int bk = 0;
#pragma unroll
      for (int k = 0; k < K_; ++k) {
        const float v = sc[t * 9 + k];
        if (v < best) { best = v; bk = k; }
      }
      a = bk;
      atomicAdd(&cnt8[bk], 1);
    }
    assign_s[t] = a;
  }
  __syncthreads();

  // per-block cluster sums -> one atomic per (k,j)
  for (int task = t; task < K_ * DH; task += 256) {
    const int k = task >> 6, j = task & 63;
    float s = 0.f;
    for (int p = 0; p < BP; ++p)
      s += (assign_s[p] == k) ? xt[p * 65 + j] : 0.f;
    if (s != 0.f) atomicAdd(&ws[(n * K_ + k) * DH + j], s);
  }
  if (t < K_ && cnt8[t] > 0) atomicAdd((int*)(ws + 2048) + n * K_ + t, cnt8[t]);
}

__global__ __launch_bounds__(256) void k_final(
    const float* __restrict__ W_a1, const float* __restrict__ b_a1,
    const float* __restrict__ W_a2, const float* __restrict__ b_a2,
    const float* __restrict__ W_out, const float* __restrict__ b_out,
    const float* __restrict__ ws, float* __restrict__ enc_cls) {
  __shared__ float xc[N_ * K_ * DH];
  __shared__ float wa[N_ * K_];
  __shared__ float As[N_ * K_];
  __shared__ int   cnts[N_ * K_];
  __shared__ float pooled[N_ * DH];
  const int t = threadIdx.x;
  const float* gsum = ws;
  const int* gcnt = (const int*)(ws + 2048);

  if (t < N_ * K_) cnts[t] = gcnt[t];
  __syncthreads();
  for (int i = t; i < N_ * K_ * DH; i += 256) {
    const int nk = i >> 6;
    const int c = cnts[nk];
    xc[i] = (c > 0) ? gsum[i] / (float)c : 0.f;
  }
  __syncthreads();
  if (t < N_ * K_) {
    float a = b_a2[0];
    for (int h = 0; h < 32; ++h) {
      float z = b_a1[h];
      for (int j = 0; j < DH; ++j) z += xc[t * DH + j] * W_a1[j * 32 + h];
      a += tanhf(z) * W_a2[h];
    }
    As[t] = (cnts[t] > 0) ? a : -100000.f;
  }
  __syncthreads();
  if (t < N_) {
    float m = -3.4e38f;
    for (int k = 0; k < K_; ++k) m = fmaxf(m, As[t * K_ + k]);
    float ssum = 0.f;
    float e[K_];
    for (int k = 0; k < K_; ++k) { e[k] = expf(As[t * K_ + k] - m); ssum += e[k]; }
    for (int k = 0; k < K_; ++k) wa[t * K_ + k] = e[k] / ssum;
  }
  __syncthreads();
  {
    const int n = t >> 6, j = t & 63;
    float s = 0.f;
    for (int k = 0; k < K_; ++k) s += xc[(n * K_ + k) * DH + j] * wa[n * K_ + k];
    pooled[t] = s;
  }
  __syncthreads();
  if (t < N_ * 32) {
    const int n = t >> 5, o = t & 31;
    float s = b_out[o];
    for (int j = 0; j < DH; ++j) s += pooled[n * DH + j] * W_out[j * 32 + o];
    enc_cls[n * 32 + o] = fmaxf(s, 0.f);
  }
}

extern "C" void kernel_launch(void* const* d_in, const int* in_sizes, int n_in,
                              void* d_out, int out_size, void* d_ws, size_t ws_size,
                              hipStream_t stream) {
  const float* x         = (const float*)d_in[0];
  const float* centroids = (const float*)d_in[1];
  const float* W_pre     = (const float*)d_in[2];
  const float* b_pre     = (const float*)d_in[3];
  const float* W_a1      = (const float*)d_in[4];
  const float* b_a1      = (const float*)d_in[5];
  const float* W_a2      = (const float*)d_in[6];
  const float* b_a2      = (const float*)d_in[7];
  const float* W_out     = (const float*)d_in[8];
  const float* b_out     = (const float*)d_in[9];

  float* out     = (float*)d_out;
  float* ws      = (float*)d_ws;
  float* enc_cls = out;
  float* out1    = out + N_ * 32;
  float* out2    = out + N_ * 32 + (size_t)N_ * P_ * DH;

  hipLaunchKernelGGL(k_prep, dim3(80), dim3(256), 0, stream, W_pre, centroids, ws);
  hipLaunchKernelGGL(k_init2, dim3(1), dim3(512), 0, stream, centroids, ws);
  hipLaunchKernelGGL(k_main, dim3((P_ + BP - 1) / BP, N_), dim3(256), 0, stream,
                     x, b_pre, out1, out2, ws);
  hipLaunchKernelGGL(k_final, dim3(1), dim3(256), 0, stream,
                     W_a1, b_a1, W_a2, b_a2, W_out, b_out, ws, enc_cls);
}

// Round 3
// 589.581 us; speedup vs baseline: 1.0937x; 1.0518x over previous
//
#include <hip/hip_runtime.h>
#include <math.h>

#define N_  4
#define P_  20000
#define DIN 1024
#define K_  8
#define DH  64
#define BP  128     // patches per block
#define NT  5       // 5 col-tiles of 16: cols 0-63 = W_pre, 64-71 = centroids, 72-79 pad

typedef float  f32x4 __attribute__((ext_vector_type(4)));
typedef short  s16x8 __attribute__((ext_vector_type(8)));
typedef unsigned int u32x4 __attribute__((ext_vector_type(4)));
typedef unsigned short ushort_t;

// ws layout (float offsets). NEEDS ws_size >= 344064 bytes.
//   [0,2048)      gsum   per-(n,k,j) cluster sums
//   [2048,2080)   gcnt   per-(n,k) counts (int)
//   [2080,2088)   c2     ||centroid_k||^2
//   [4096,45056)  Bth    bf16-hi plane of B^T  [80 cols][1024 k] (ushort)
//   [45056,86016) Btl    bf16-lo plane of B^T  (ushort)

union FragU { u32x4 u; s16x8 s; };

__device__ __forceinline__ void async_ld16(const float* g, float* l) {
  __builtin_amdgcn_global_load_lds(
      (const __attribute__((address_space(1))) unsigned int*)g,
      (__attribute__((address_space(3))) unsigned int*)l, 16, 0, 0);
}

// blocks 0..79: build B^T bf16 hi/lo planes; block 80: zero accumulators + c2
__global__ __launch_bounds__(512) void k_pre(const float* __restrict__ W_pre,
                                             const float* __restrict__ centroids,
                                             float* __restrict__ ws) {
  const int t = threadIdx.x;
  const int b = blockIdx.x;
  if (b < 80) {
    const int c = b;
    ushort_t* Bth = (ushort_t*)(ws + 4096);
    ushort_t* Btl = (ushort_t*)(ws + 45056);
    for (int d = t; d < DIN; d += 512) {
      float v = 0.f;
      if (c < 64)      v = W_pre[(size_t)d * DH + c];
      else if (c < 72) v = centroids[(size_t)(c - 64) * DIN + d];
      unsigned u = __float_as_uint(v);
      unsigned r = u + 0x7FFFu + ((u >> 16) & 1u);     // RTN to bf16
      unsigned hb = r & 0xFFFF0000u;
      float lo = v - __uint_as_float(hb);
      unsigned ul = __float_as_uint(lo);
      unsigned rl = ul + 0x7FFFu + ((ul >> 16) & 1u);
      Bth[(size_t)c * DIN + d] = (ushort_t)(hb >> 16);
      Btl[(size_t)c * DIN + d] = (ushort_t)(rl >> 16);
    }
  } else {
    int* gcnt = (int*)(ws + 2048);
    for (int i = t; i < N_ * K_ * DH; i += 512) ws[i] = 0.f;
    if (t < N_ * K_) gcnt[t] = 0;
    const int w = t >> 6, lane = t & 63;
    float s = 0.f;
    for (int d = lane; d < DIN; d += 64) {
      float v = centroids[(size_t)w * DIN + d];
      s += v * v;
    }
    for (int off = 32; off > 0; off >>= 1) s += __shfl_down(s, off, 64);
    if (lane == 0) ws[2080 + w] = s;
  }
}

__global__ __launch_bounds__(256) void k_main(
    const float* __restrict__ x, const float* __restrict__ b_pre,
    float* __restrict__ out1, float* __restrict__ out2, float* __restrict__ ws) {
  // 2 async-staged x buffers, 128 rows x 64 floats each (XOR-16 granule swizzle).
  // After the K-loop the whole region is reused as the xp tile (stride 65).
  __shared__ float smem[2 * BP * 64];
  __shared__ float sc[BP * 9];
  __shared__ int   assign_s[BP];
  __shared__ int   cnt8[K_];
  __shared__ float c2s[K_];

  const int t = threadIdx.x;
  const int w = t >> 6, l = t & 63;
  const int m = l & 15, q4 = l >> 4;
  const int quad8 = q4 << 3;
  const int n = blockIdx.y;
  const int p0 = blockIdx.x * BP;
  const int validP = (P_ - p0) < BP ? (P_ - p0) : BP;

  const ushort_t* Bth = (const ushort_t*)(ws + 4096);
  const ushort_t* Btl = (const ushort_t*)(ws + 45056);

  if (t < K_) { cnt8[t] = 0; c2s[t] = ws[2080 + t]; }

  f32x4 acc[2][NT];
#pragma unroll
  for (int rg = 0; rg < 2; ++rg)
#pragma unroll
    for (int tl = 0; tl < NT; ++tl) acc[rg][tl] = (f32x4){0.f, 0.f, 0.f, 0.f};

  const float* xbase = x + (size_t)n * P_ * DIN;

  // staging plan: wave w stages rows [32w, 32w+32), 8 DMA instrs of 4 rows each.
  // LDS granule (row, gs) holds logical granule g = gs ^ (row & 15)  (16B granules).
  const float* gsrc[8];
  float* ldst[8];
#pragma unroll
  for (int ii = 0; ii < 8; ++ii) {
    const int R = w * 32 + ii * 4;        // wave-uniform start row
    const int row = R + q4;               // this lane's row
    const int g = m ^ (row & 15);         // logical granule this lane fetches
    int gp = p0 + row; gp = gp < P_ ? gp : P_ - 1;
    gsrc[ii] = xbase + (size_t)gp * DIN + 4 * g;
    ldst[ii] = smem + R * 64;             // wave-uniform LDS base (+ buf*8192)
  }

  // prologue: chunk 0 -> buffer 0
#pragma unroll
  for (int ii = 0; ii < 8; ++ii) async_ld16(gsrc[ii], ldst[ii]);

  for (int ch = 0; ch < 16; ++ch) {
    __syncthreads();   // drains chunk-ch DMA (issued one iter ago) + prior reads
    if (ch < 15) {
      const int nb = (ch + 1) & 1;
#pragma unroll
      for (int ii = 0; ii < 8; ++ii)
        async_ld16(gsrc[ii] + (ch + 1) * 64, ldst[ii] + nb * 8192);
    }
    const float* bufp = smem + (ch & 1) * 8192;

#pragma unroll
    for (int kk = 0; kk < 2; ++kk) {
      const int kb = ch * 64 + kk * 32 + quad8;
      FragU bh[NT], bl[NT];
#pragma unroll
      for (int tl = 0; tl < NT; ++tl) {
        const size_t off = (size_t)(tl * 16 + m) * DIN + kb;
        bh[tl].u = *(const u32x4*)(Bth + off);
        bl[tl].u = *(const u32x4*)(Btl + off);
      }
#pragma unroll
      for (int rg = 0; rg < 2; ++rg) {
        const int row = 32 * w + 16 * rg + m;     // row & 15 == m
        const int ga = kk * 8 + (q4 << 1);        // logical granule of first f32x4
        f32x4 a0 = *(const f32x4*)(bufp + row * 64 + 4 * (ga ^ m));
        f32x4 a1 = *(const f32x4*)(bufp + row * 64 + 4 * ((ga + 1) ^ m));
        float f[8];
#pragma unroll
        for (int e = 0; e < 4; ++e) { f[e] = a0[e]; f[4 + e] = a1[e]; }
        FragU ah, al;
#pragma unroll
        for (int q = 0; q < 4; ++q) {
          const unsigned u0 = __float_as_uint(f[2 * q]);
          const unsigned u1 = __float_as_uint(f[2 * q + 1]);
          ah.u[q] = (u0 >> 16) | (u1 & 0xFFFF0000u);           // hi = trunc-bf16
          const float l0 = f[2 * q]     - __uint_as_float(u0 & 0xFFFF0000u);
          const float l1 = f[2 * q + 1] - __uint_as_float(u1 & 0xFFFF0000u);
          al.u[q] = (__float_as_uint(l0) >> 16) | (__float_as_uint(l1) & 0xFFFF0000u);
        }
#pragma unroll
        for (int tl = 0; tl < NT; ++tl) {
          acc[rg][tl] = __builtin_amdgcn_mfma_f32_16x16x32_bf16(ah.s, bh[tl].s, acc[rg][tl], 0, 0, 0);
          acc[rg][tl] = __builtin_amdgcn_mfma_f32_16x16x32_bf16(ah.s, bl[tl].s, acc[rg][tl], 0, 0, 0);
          acc[rg][tl] = __builtin_amdgcn_mfma_f32_16x16x32_bf16(al.s, bh[tl].s, acc[rg][tl], 0, 0, 0);
        }
      }
    }
  }
  __syncthreads();   // all LDS x reads done; reuse smem as xp tile (stride 65)

  // epilogue: bias+relu, write enc_seq twice, xp -> LDS
#pragma unroll
  for (int tl = 0; tl < 4; ++tl) {
    const int col = tl * 16 + m;
    const float bb = b_pre[col];
#pragma unroll
    for (int rg = 0; rg < 2; ++rg) {
#pragma unroll
      for (int r = 0; r < 4; ++r) {
        const int row = 32 * w + 16 * rg + (q4 << 2) + r;   // C layout: row=(lane>>4)*4+reg
        float v = acc[rg][tl][r] + bb;
        v = v > 0.f ? v : 0.f;
        smem[row * 65 + col] = v;
        if (row < validP) {
          const size_t o = (((size_t)(n * P_ + p0 + row)) << 6) + col;
          out1[o] = v;
          out2[o] = v;
        }
      }
    }
  }
  // scores from col-tile 4 (cols 64-71 = centroid dots)
  if (m < K_) {
#pragma unroll
    for (int rg = 0; rg < 2; ++rg)
#pragma unroll
      for (int r = 0; r < 4; ++r) {
        const int row = 32 * w + 16 * rg + (q4 << 2) + r;
        sc[row * 9 + m] = c2s[m] - 2.f * acc[rg][4][r];
      }
  }
  __syncthreads();

  if (t < BP) {
    int a = -1;
    if (t < validP) {
      float best = 3.4e38f; int bk = 0;
#pragma unroll
      for (int k = 0; k < K_; ++k) {
        const float v = sc[t * 9 + k];
        if (v < best) { best = v; bk = k; }
      }
      a = bk;
      atomicAdd(&cnt8[bk], 1);
    }
    assign_s[t] = a;
  }
  __syncthreads();

  // per-block cluster sums -> one atomic per (k,j)
  for (int task = t; task < K_ * DH; task += 256) {
    const int k = task >> 6, j = task & 63;
    float s = 0.f;
    for (int p = 0; p < BP; ++p)
      s += (assign_s[p] == k) ? smem[p * 65 + j] : 0.f;
    if (s != 0.f) atomicAdd(&ws[(n * K_ + k) * DH + j], s);
  }
  if (t < K_ && cnt8[t] > 0) atomicAdd((int*)(ws + 2048) + n * K_ + t, cnt8[t]);
}

__global__ __launch_bounds__(256) void k_final(
    const float* __restrict__ W_a1, const float* __restrict__ b_a1,
    const float* __restrict__ W_a2, const float* __restrict__ b_a2,
    const float* __restrict__ W_out, const float* __restrict__ b_out,
    const float* __restrict__ ws, float* __restrict__ enc_cls) {
  __shared__ float xc[N_ * K_ * DH];
  __shared__ float wa[N_ * K_];
  __shared__ float As[N_ * K_];
  __shared__ int   cnts[N_ * K_];
  __shared__ float pooled[N_ * DH];
  const int t = threadIdx.x;
  const float* gsum = ws;
  const int* gcnt = (const int*)(ws + 2048);

  if (t < N_ * K_) cnts[t] = gcnt[t];
  __syncthreads();
  for (int i = t; i < N_ * K_ * DH; i += 256) {
    const int nk = i >> 6;
    const int c = cnts[nk];
    xc[i] = (c > 0) ? gsum[i] / (float)c : 0.f;
  }
  __syncthreads();
  if (t < N_ * K_) {
    float a = b_a2[0];
    for (int h = 0; h < 32; ++h) {
      float z = b_a1[h];
      for (int j = 0; j < DH; ++j) z += xc[t * DH + j] * W_a1[j * 32 + h];
      a += tanhf(z) * W_a2[h];
    }
    As[t] = (cnts[t] > 0) ? a : -100000.f;
  }
  __syncthreads();
  if (t < N_) {
    float mx = -3.4e38f;
    for (int k = 0; k < K_; ++k) mx = fmaxf(mx, As[t * K_ + k]);
    float ssum = 0.f;
    float e[K_];
    for (int k = 0; k < K_; ++k) { e[k] = expf(As[t * K_ + k] - mx); ssum += e[k]; }
    for (int k = 0; k < K_; ++k) wa[t * K_ + k] = e[k] / ssum;
  }
  __syncthreads();
  {
    const int n = t >> 6, j = t & 63;
    float s = 0.f;
    for (int k = 0; k < K_; ++k) s += xc[(n * K_ + k) * DH + j] * wa[n * K_ + k];
    pooled[t] = s;
  }
  __syncthreads();
  if (t < N_ * 32) {
    const int n = t >> 5, o = t & 31;
    float s = b_out[o];
    for (int j = 0; j < DH; ++j) s += pooled[n * DH + j] * W_out[j * 32 + o];
    enc_cls[n * 32 + o] = fmaxf(s, 0.f);
  }
}

extern "C" void kernel_launch(void* const* d_in, const int* in_sizes, int n_in,
                              void* d_out, int out_size, void* d_ws, size_t ws_size,
                              hipStream_t stream) {
  const float* x         = (const float*)d_in[0];
  const float* centroids = (const float*)d_in[1];
  const float* W_pre     = (const float*)d_in[2];
  const float* b_pre     = (const float*)d_in[3];
  const float* W_a1      = (const float*)d_in[4];
  const float* b_a1      = (const float*)d_in[5];
  const float* W_a2      = (const float*)d_in[6];
  const float* b_a2      = (const float*)d_in[7];
  const float* W_out     = (const float*)d_in[8];
  const float* b_out     = (const float*)d_in[9];

  float* out     = (float*)d_out;
  float* ws      = (float*)d_ws;
  float* enc_cls = out;
  float* out1    = out + N_ * 32;
  float* out2    = out + N_ * 32 + (size_t)N_ * P_ * DH;

  hipLaunchKernelGGL(k_pre, dim3(81), dim3(512), 0, stream, W_pre, centroids, ws);
  hipLaunchKernelGGL(k_main, dim3((P_ + BP - 1) / BP, N_), dim3(256), 0, stream,
                     x, b_pre, out1, out2, ws);
  hipLaunchKernelGGL(k_final, dim3(1), dim3(256), 0, stream,
                     W_a1, b_a1, W_a2, b_a2, W_out, b_out, ws, enc_cls);
}